// Round 1
// 379.353 us; speedup vs baseline: 1.0293x; 1.0293x over previous
//
#include <hip/hip_runtime.h>
#include <hip/hip_bf16.h>
#include <stdint.h>

// B=1024, N=16, D=64, H=64, A=64 -> 16384 nodes. All tensors fp32.
#define NNODE 16384
#define TAU_ 0.01f
#define EPSG 1e-10f

// ---- workspace layout (float offsets); total 1,114,112 floats = 4.25 MB ----
#define OFF_WENC 0
#define OFF_BENC 4096
// bf16 hi/lo weight copies (reuse the old f32 Wih/Whh slots)
#define OFF_WIHF_H 4160      // 192x128 bf16 = 24576 ushort = 12288 fl
#define OFF_WIHF_L 16448
#define OFF_WHHF_H 28736     // 192x64 bf16 = 12288 ushort = 6144 fl
#define OFF_BIHF 41024
#define OFF_BHHF 41216
#define OFF_WIHB_H 41408
#define OFF_WIHB_L 53696
#define OFF_WHHB_H 65984
#define OFF_BIHB 78272
#define OFF_BHHB 78464
#define OFF_WHARD 78656
#define OFF_BHARD 78912
#define OFF_WQ 78914
#define OFF_WK 83010
#define OFF_WV 87106
#define OFF_BV 91202
#define OFF_WIHC 91266
#define OFF_WHHC 103554
#define OFF_BIHC 115842
#define OFF_BHHC 116034
#define OFF_WENCT_H 118784   // Wenc^T bf16 hi: 64x64 = 4096 ushort = 2048 fl
#define OFF_WENCT_L 120832
#define OFF_YF 131072
#define OFF_YB (OFF_YF + 491520)
#define WS_FLOATS (OFF_YB + 491520)

typedef float  v4f __attribute__((ext_vector_type(4)));
typedef short  v8s __attribute__((ext_vector_type(8)));

__device__ __forceinline__ float sigf(float x){ return 1.0f/(1.0f + __expf(-x)); }
__device__ __forceinline__ float tanhfast(float x){ return 1.0f - 2.0f/(__expf(2.0f*x)+1.0f); }
__device__ __forceinline__ unsigned short f2bf(float f){
  __hip_bfloat16 h = __float2bfloat16(f);
  return *reinterpret_cast<unsigned short*>(&h);
}
__device__ __forceinline__ float bf2f(unsigned short u){
  union { unsigned int i; float f; } v; v.i = ((unsigned int)u) << 16; return v.f;
}

// ---------------- K0: copy f32 weights still needed as f32 ----------------
struct Prep {
  const float* s[20];
  int n[20];
  int o[20];
};
__global__ void k_prep(Prep p, float* __restrict__ ws){
  int a = blockIdx.y;
  int i = blockIdx.x * blockDim.x + threadIdx.x;
  if (i < p.n[a]) ws[p.o[a] + i] = p.s[a][i];
}

// ---------------- K0b: bf16 hi/lo splits of the MFMA weights ----------------
// a=0: Wenc^T (transpose+split), a=1/2: Wih_f/Wih_b (flat split),
// a=3/4: Whh_f/Whh_b (hi only; bit-identical to the old f2bf path).
__global__ void k_prep2(const float* __restrict__ wenc,
                        const float* __restrict__ wihf, const float* __restrict__ wihb,
                        const float* __restrict__ whhf, const float* __restrict__ whhb,
                        float* __restrict__ ws){
  int a = blockIdx.y;
  int i = blockIdx.x * blockDim.x + threadIdx.x;
  if (a == 0){
    if (i < 4096){
      float x = wenc[((i & 63) << 6) | (i >> 6)];   // WencT[l][d] = Wenc[d][l]
      unsigned short h = f2bf(x);
      unsigned short l = f2bf(x - bf2f(h));
      ((unsigned short*)(ws + OFF_WENCT_H))[i] = h;
      ((unsigned short*)(ws + OFF_WENCT_L))[i] = l;
    }
  } else if (a == 1 || a == 2){
    if (i < 24576){
      float x = (a == 1 ? wihf : wihb)[i];
      unsigned short h = f2bf(x);
      unsigned short l = f2bf(x - bf2f(h));
      ((unsigned short*)(ws + (a == 1 ? OFF_WIHF_H : OFF_WIHB_H)))[i] = h;
      ((unsigned short*)(ws + (a == 1 ? OFF_WIHF_L : OFF_WIHB_L)))[i] = l;
    }
  } else {
    if (i < 12288){
      float x = (a == 3 ? whhf : whhb)[i];
      ((unsigned short*)(ws + (a == 3 ? OFF_WHHF_H : OFF_WHHB_H)))[i] = f2bf(x);
    }
  }
}

// ---------------- K1: bidirectional 15-step GRU via bf16 MFMA ---------------
// grid 512 (dir = bid>>8).  512 thr = 8 waves; wave w: lw=w>>2, nw=w&3.
// NEW: setup phases (h_enc, u2, cb) are MFMA GEMMs with split-bf16 (hi*hi +
// hi*lo + lo*hi, err ~2^-17 ~= fp32) instead of per-thread fp32 dot products.
// Weights pre-split to bf16 hi/lo by k_prep2 -> frag load = one 16B load.
// Loop + reducer unchanged (h stride 80 -> 88 for bank-conflict relief).
__global__ __launch_bounds__(512, 4) void k_gru(const float* __restrict__ obs,
                                                float* __restrict__ ws){
  __shared__ float smem[18176];               // 71 KB -> 2 blocks/CU
  float* s_u2 = smem;                         // [j-node][196] rows g*64+l : 12544
  unsigned short* s_obs_h = (unsigned short*)(smem + 12544); // obs/h_enc hi [64][72]
  unsigned short* s_obs_l = s_obs_h + 4608;                  // lo [64][72]
  unsigned short* s_hbu   = (unsigned short*)(smem + 12544); // loop h: 2 x [64][88] (aliases)

  const int tid = threadIdx.x;
  const int nl  = tid & 63;
  const int grp = __builtin_amdgcn_readfirstlane(tid >> 6);
  const int dir = blockIdx.x >> 8;
  const int base = (blockIdx.x & 255) * 64;
  const int lw = grp >> 2;                    // 0,1 : l-range 32*lw..+32 (loop rows)
  const int nw = grp & 3;                     // node-tile
  const int q  = nl >> 4;                     // quad
  const int i_c = nl & 15;
  const int node = 16*nw + i_c;               // this thread's target node (local)

  // P0: stage obs as bf16 hi/lo, B-frag friendly layout [node][72]
  {
    float4 a = *(const float4*)&obs[base*64 + tid*8];
    float4 b = *(const float4*)&obs[base*64 + tid*8 + 4];
    int nn = tid >> 3, d0 = (tid & 7)*8;
    union { v8s v; unsigned short u[8]; } H, L;
    float xs[8] = {a.x,a.y,a.z,a.w,b.x,b.y,b.z,b.w};
    #pragma unroll
    for (int e = 0; e < 8; e++){
      H.u[e] = f2bf(xs[e]);
      L.u[e] = f2bf(xs[e] - bf2f(H.u[e]));
    }
    *(v8s*)&s_obs_h[nn*72 + d0] = H.v;
    *(v8s*)&s_obs_l[nn*72 + d0] = L.v;
  }
  __syncthreads();

  // P1: h_enc = relu(obs @ Wenc + b_enc) via MFMA.  rows=l (A=Wenc^T), cols=node.
  // Wave (lw,nw): tiles lT = 2*lw+{0,1}, n-tile nw.  In-place write-back.
  const float* benc = ws + OFF_BENC;
  const unsigned short* wtH = (const unsigned short*)(ws + OFF_WENCT_H);
  const unsigned short* wtL = (const unsigned short*)(ws + OFF_WENCT_L);
  v4f dEnc[2];
  {
    v8s obH[2], obL[2];
    #pragma unroll
    for (int kc = 0; kc < 2; kc++){
      int ba = node*72 + kc*32 + q*8;
      obH[kc] = *(const v8s*)&s_obs_h[ba];
      obL[kc] = *(const v8s*)&s_obs_l[ba];
    }
    #pragma unroll
    for (int tt = 0; tt < 2; tt++){
      int lT = 2*lw + tt;
      float4 bi = *(const float4*)&benc[16*lT + 4*q];
      v4f d = (v4f){bi.x, bi.y, bi.z, bi.w};
      #pragma unroll
      for (int kc = 0; kc < 2; kc++){
        int aa = (16*lT + i_c)*64 + kc*32 + q*8;
        v8s aH = *(const v8s*)&wtH[aa];
        v8s aL = *(const v8s*)&wtL[aa];
        d = __builtin_amdgcn_mfma_f32_16x16x32_bf16(aH, obH[kc], d, 0,0,0);
        d = __builtin_amdgcn_mfma_f32_16x16x32_bf16(aH, obL[kc], d, 0,0,0);
        d = __builtin_amdgcn_mfma_f32_16x16x32_bf16(aL, obH[kc], d, 0,0,0);
      }
      dEnc[tt] = d;
    }
  }
  __syncthreads();   // all obs reads done -> safe to overwrite in place
  #pragma unroll
  for (int tt = 0; tt < 2; tt++){
    int lT = 2*lw + tt;
    unsigned short hh[4], ll[4];
    #pragma unroll
    for (int r = 0; r < 4; r++){
      float v = fmaxf(dEnc[tt][r], 0.0f);
      hh[r] = f2bf(v);
      ll[r] = f2bf(v - bf2f(hh[r]));
    }
    int wa = node*72 + 16*lT + 4*q;   // D: col=node, rows 16lT+4q+r (consecutive)
    *(uint2*)&s_obs_h[wa] = make_uint2((unsigned)hh[0] | ((unsigned)hh[1]<<16),
                                       (unsigned)hh[2] | ((unsigned)hh[3]<<16));
    *(uint2*)&s_obs_l[wa] = make_uint2((unsigned)ll[0] | ((unsigned)ll[1]<<16),
                                       (unsigned)ll[2] | ((unsigned)ll[3]<<16));
  }
  __syncthreads();

  const float* bih = ws + (dir ? OFF_BIHB : OFF_BIHF);
  const float* bhh = ws + (dir ? OFF_BHHB : OFF_BHHF);
  const unsigned short* wiH = (const unsigned short*)(ws + (dir ? OFF_WIHB_H : OFF_WIHF_H));
  const unsigned short* wiL = (const unsigned short*)(ws + (dir ? OFF_WIHB_L : OFF_WIHF_L));
  const unsigned short* whH = (const unsigned short*)(ws + (dir ? OFF_WHHB_H : OFF_WHHF_H));

  // shared B-frags: h_enc hi/lo for this wave's node-tile (cols 16nw..)
  v8s hbH[2], hbL[2];
  #pragma unroll
  for (int kc = 0; kc < 2; kc++){
    int ba = node*72 + kc*32 + q*8;
    hbH[kc] = *(const v8s*)&s_obs_h[ba];
    hbL[kc] = *(const v8s*)&s_obs_l[ba];
  }

  // P2a: u2[j][row] = WihR . h_enc[j]  (A = Wih[:,64:128]).  Wave: M-tiles 6lw+m.
  #pragma unroll
  for (int m = 0; m < 6; m++){
    int T = 6*lw + m;
    v4f d = (v4f){0.f,0.f,0.f,0.f};
    #pragma unroll
    for (int kc = 0; kc < 2; kc++){
      int aa = (16*T + i_c)*128 + 64 + kc*32 + q*8;
      v8s aH = *(const v8s*)&wiH[aa];
      v8s aL = *(const v8s*)&wiL[aa];
      d = __builtin_amdgcn_mfma_f32_16x16x32_bf16(aH, hbH[kc], d, 0,0,0);
      d = __builtin_amdgcn_mfma_f32_16x16x32_bf16(aH, hbL[kc], d, 0,0,0);
      d = __builtin_amdgcn_mfma_f32_16x16x32_bf16(aL, hbH[kc], d, 0,0,0);
    }
    *(v4f*)&s_u2[node*196 + 16*T + 4*q] = d;   // rows 16T+4q..+3, col=node
  }

  // P2b: cb = bias + WihL . h_i  -> lands directly in the loop's C-layout.
  // Tile rows 64g+32lw+16t2 (cols 16nw..) = exactly this thread's (l0, node).
  v4f cbr[2], cbz[2], cbn[2], bhn4[2];
  #pragma unroll
  for (int g = 0; g < 3; g++){
    #pragma unroll
    for (int t2 = 0; t2 < 2; t2++){
      int row0 = 64*g + 32*lw + 16*t2 + 4*q;
      float4 bi = *(const float4*)&bih[row0];
      v4f d;
      if (g < 2){
        float4 bh = *(const float4*)&bhh[row0];
        d = (v4f){bi.x+bh.x, bi.y+bh.y, bi.z+bh.z, bi.w+bh.w};
      } else {
        d = (v4f){bi.x, bi.y, bi.z, bi.w};
      }
      int T = (64*g + 32*lw + 16*t2) >> 4;
      #pragma unroll
      for (int kc = 0; kc < 2; kc++){
        int aa = (16*T + i_c)*128 + kc*32 + q*8;   // left half of Wih
        v8s aH = *(const v8s*)&wiH[aa];
        v8s aL = *(const v8s*)&wiL[aa];
        d = __builtin_amdgcn_mfma_f32_16x16x32_bf16(aH, hbH[kc], d, 0,0,0);
        d = __builtin_amdgcn_mfma_f32_16x16x32_bf16(aH, hbL[kc], d, 0,0,0);
        d = __builtin_amdgcn_mfma_f32_16x16x32_bf16(aL, hbH[kc], d, 0,0,0);
      }
      if (g == 0) cbr[t2] = d; else if (g == 1) cbz[t2] = d; else cbn[t2] = d;
    }
  }
  #pragma unroll
  for (int t2 = 0; t2 < 2; t2++){
    int row0 = 128 + 32*lw + 16*t2 + 4*q;
    float4 nh = *(const float4*)&bhh[row0];
    bhn4[t2] = (v4f){nh.x, nh.y, nh.z, nh.w};
  }

  // P2c: Whh -> persistent bf16 A-fragments (pre-split, single 16B load each).
  v8s afr[2][2], afz[2][2], afn[2][2];
  #pragma unroll
  for (int t2 = 0; t2 < 2; t2++){
    #pragma unroll
    for (int kc = 0; kc < 2; kc++){
      #pragma unroll
      for (int g = 0; g < 3; g++){
        int row = g*64 + 32*lw + 16*t2 + i_c;
        v8s a = *(const v8s*)&whH[row*64 + kc*32 + q*8];
        if (g == 0) afr[t2][kc] = a; else if (g == 1) afz[t2][kc] = a; else afn[t2][kc] = a;
      }
    }
  }
  __syncthreads();   // u2 visible; all s_obs reads done; s_hbu (alias) writable

  // P3: 15-step recurrence (unchanged; h stride 80 -> 88 ushorts)
  const float* whard = ws + OFF_WHARD + dir*128;
  float* yout        = ws + (dir ? OFF_YB : OFF_YF);

  float hv[8];
  #pragma unroll
  for (int m = 0; m < 8; m++) hv[m] = 0.0f;

  for (int kk = 0; kk < 15; kk++){
    const int t  = dir ? (14 - kk) : kk;
    const int j  = t + (t >= i_c ? 1 : 0);
    const int jl = 16*nw + j;
    const int rb = kk & 1;            // read buffer (valid for kk>0)
    const int wb = (kk + 1) & 1;      // write buffer

    v8s b0, b1;
    if (kk > 0){
      const unsigned short* rp = s_hbu + rb*5632 + node*88 + q*8;
      b0 = *(const v8s*)(rp);
      b1 = *(const v8s*)(rp + 32);
    }

    #pragma unroll
    for (int t2 = 0; t2 < 2; t2++){
      int l0 = 32*lw + 16*t2 + 4*q;
      v4f dr = cbr[t2], dz = cbz[t2];
      v4f dn = (v4f){0.f,0.f,0.f,0.f};
      if (kk > 0){
        dr = __builtin_amdgcn_mfma_f32_16x16x32_bf16(afr[t2][0], b0, dr, 0,0,0);
        dr = __builtin_amdgcn_mfma_f32_16x16x32_bf16(afr[t2][1], b1, dr, 0,0,0);
        dz = __builtin_amdgcn_mfma_f32_16x16x32_bf16(afz[t2][0], b0, dz, 0,0,0);
        dz = __builtin_amdgcn_mfma_f32_16x16x32_bf16(afz[t2][1], b1, dz, 0,0,0);
        dn = __builtin_amdgcn_mfma_f32_16x16x32_bf16(afn[t2][0], b0, dn, 0,0,0);
        dn = __builtin_amdgcn_mfma_f32_16x16x32_bf16(afn[t2][1], b1, dn, 0,0,0);
      }
      v4f ur = *(const v4f*)&s_u2[jl*196 +       l0];
      v4f uz = *(const v4f*)&s_u2[jl*196 +  64 + l0];
      v4f un = *(const v4f*)&s_u2[jl*196 + 128 + l0];
      float hn[4];
      #pragma unroll
      for (int r = 0; r < 4; r++){
        float rg = sigf(dr[r] + ur[r]);
        float zg = sigf(dz[r] + uz[r]);
        float ng = tanhfast(cbn[t2][r] + un[r] + rg*(bhn4[t2][r] + dn[r]));
        float hnew = (1.0f - zg)*ng + zg*hv[t2*4+r];
        hv[t2*4+r] = hnew;
        hn[r] = hnew;
      }
      unsigned int p0 = (unsigned int)f2bf(hn[0]) | ((unsigned int)f2bf(hn[1]) << 16);
      unsigned int p1 = (unsigned int)f2bf(hn[2]) | ((unsigned int)f2bf(hn[3]) << 16);
      *(uint2*)(s_hbu + wb*5632 + node*88 + l0) = make_uint2(p0, p1);
    }
    __syncthreads();

    // reducer: y[node][t] = h_new . W_hard rows (fwd: l, bwd: 64+l)
    if (tid < 64){
      const unsigned short* hb = s_hbu + wb*5632 + tid*88;
      float a0 = 0.f, a1 = 0.f;
      #pragma unroll
      for (int c = 0; c < 16; c++){
        uint2 hw = *(const uint2*)(hb + c*4);
        float f0 = bf2f((unsigned short)(hw.x & 0xffff));
        float f1 = bf2f((unsigned short)(hw.x >> 16));
        float f2 = bf2f((unsigned short)(hw.y & 0xffff));
        float f3 = bf2f((unsigned short)(hw.y >> 16));
        int l = c*4;
        a0 += f0*whard[(l  )*2] + f1*whard[(l+1)*2] + f2*whard[(l+2)*2] + f3*whard[(l+3)*2];
        a1 += f0*whard[(l  )*2+1] + f1*whard[(l+1)*2+1] + f2*whard[(l+2)*2+1] + f3*whard[(l+3)*2+1];
      }
      *(float2*)&yout[((base + tid)*15 + t)*2] = make_float2(a0, a1);
    }
  }
}

// ---------------- K2: qkv + gumbel + attention + final GRU cell -------------
// 256 thr = 4 grps x 16. Sequential low-live passes (unchanged).
__global__ __launch_bounds__(256, 1) void k_attn(const float* __restrict__ obs,
                                                 const float* __restrict__ hid,
                                                 const float* __restrict__ gum,
                                                 float* __restrict__ ws,
                                                 float* __restrict__ out){
  __shared__ float smem[16384];          // 64 KB
  float* s_k  = smem;                    // 4096  [a][node]
  float* s_v  = smem + 4096;             // 4096
  float* s_x  = smem + 8192;             // 4352  [node][68]: obs -> h_enc -> x
  float* s_sp = smem + 12544;            // 3840  score partials
  float* s_h0 = smem;                    // 4352, aliases dead s_k/s_v (late phases)
  const int tid = threadIdx.x;
  const int nl  = tid & 63;
  const int grp = __builtin_amdgcn_readfirstlane(tid >> 6);
  const int base = blockIdx.x * 64;
  const int node = base + nl;

  for (int k = tid; k < 4096; k += 256)
    s_x[(k>>6)*68 + (k&63)] = obs[base*64 + k];
  __syncthreads();

  const float* wenc = ws + OFF_WENC; const float* benc = ws + OFF_BENC;
  {
    float he[16];
    #pragma unroll
    for (int il = 0; il < 16; il++) he[il] = benc[grp*16 + il];
    #pragma unroll
    for (int dq = 0; dq < 16; dq++){
      float4 o4 = *(const float4*)&s_x[nl*68 + 4*dq];
      #pragma unroll
      for (int il = 0; il < 16; il++){
        int l = grp*16 + il;
        he[il] += o4.x*wenc[(4*dq+0)*64+l] + o4.y*wenc[(4*dq+1)*64+l]
                + o4.z*wenc[(4*dq+2)*64+l] + o4.w*wenc[(4*dq+3)*64+l];
      }
    }
    __syncthreads();
    #pragma unroll
    for (int il = 0; il < 16; il++) s_x[nl*68 + grp*16 + il] = fmaxf(he[il], 0.0f);
  }
  __syncthreads();

  const float* wq = ws+OFF_WQ; const float* wk = ws+OFF_WK;
  const float* wv = ws+OFF_WV; const float* bv = ws+OFF_BV;
  {
    float ak[16];
    #pragma unroll
    for (int il = 0; il < 16; il++) ak[il] = 0.f;
    #pragma unroll
    for (int dq = 0; dq < 16; dq++){
      float4 h4 = *(const float4*)&s_x[nl*68 + 4*dq];
      #pragma unroll
      for (int il = 0; il < 16; il++){
        int a = grp*16 + il;
        ak[il] += h4.x*wk[(4*dq+0)*64+a] + h4.y*wk[(4*dq+1)*64+a]
                + h4.z*wk[(4*dq+2)*64+a] + h4.w*wk[(4*dq+3)*64+a];
      }
    }
    #pragma unroll
    for (int il = 0; il < 16; il++) s_k[(grp*16+il)*64 + nl] = ak[il];
  }
  {
    float av[16];
    #pragma unroll
    for (int il = 0; il < 16; il++) av[il] = bv[grp*16+il];
    #pragma unroll
    for (int dq = 0; dq < 16; dq++){
      float4 h4 = *(const float4*)&s_x[nl*68 + 4*dq];
      #pragma unroll
      for (int il = 0; il < 16; il++){
        int a = grp*16 + il;
        av[il] += h4.x*wv[(4*dq+0)*64+a] + h4.y*wv[(4*dq+1)*64+a]
                + h4.z*wv[(4*dq+2)*64+a] + h4.w*wv[(4*dq+3)*64+a];
      }
    }
    #pragma unroll
    for (int il = 0; il < 16; il++) s_v[(grp*16+il)*64 + nl] = fmaxf(av[il], 0.f);
  }
  float aq[16];
  #pragma unroll
  for (int il = 0; il < 16; il++) aq[il] = 0.f;
  #pragma unroll
  for (int dq = 0; dq < 16; dq++){
    float4 h4 = *(const float4*)&s_x[nl*68 + 4*dq];
    #pragma unroll
    for (int il = 0; il < 16; il++){
      int a = grp*16 + il;
      aq[il] += h4.x*wq[(4*dq+0)*64+a] + h4.y*wq[(4*dq+1)*64+a]
              + h4.z*wq[(4*dq+2)*64+a] + h4.w*wq[(4*dq+3)*64+a];
    }
  }
  __syncthreads();

  const int i_b = nl & 15, jbase = nl & 48;
  #pragma unroll
  for (int t = 0; t < 15; t++){
    int jl = jbase | (t + (t >= i_b ? 1 : 0));
    float s = 0.f;
    #pragma unroll
    for (int il = 0; il < 16; il++) s += aq[il]*s_k[(grp*16+il)*64 + jl];
    s_sp[t*256 + grp*64 + nl] = s;
  }
  __syncthreads();

  float coeff[15];
  {
    float sc[15];
    float m = -1e30f;
    #pragma unroll
    for (int t = 0; t < 15; t++){
      float s = (s_sp[t*256+nl] + s_sp[t*256+64+nl] +
                 s_sp[t*256+128+nl] + s_sp[t*256+192+nl]) * 0.125f;
      sc[t] = s; m = fmaxf(m, s);
    }
    float den = 0.f;
    #pragma unroll
    for (int t = 0; t < 15; t++){ sc[t] = __expf(sc[t]-m); den += sc[t]; }
    float rden = 1.0f/den;
    const float bh0 = ws[OFF_BHARD], bh1 = ws[OFF_BHARD+1];
    const float* yF = ws + OFF_YF; const float* yB = ws + OFF_YB;
    #pragma unroll
    for (int t = 0; t < 15; t++){
      int rowb = (node*15 + t)*2;
      float y0 = yF[rowb]   + yB[rowb]   + bh0;
      float y1 = yF[rowb+1] + yB[rowb+1] + bh1;
      float2 u2 = *(const float2*)&gum[rowb];
      float g0 = -__logf(-__logf(u2.x + EPSG) + EPSG);
      float g1 = -__logf(-__logf(u2.y + EPSG) + EPSG);
      float w  = sigf(((y1+g1) - (y0+g0)) * (1.0f/TAU_));
      coeff[t] = sc[t]*rden*w;
    }
  }

  {
    float xa[16];
    #pragma unroll
    for (int il = 0; il < 16; il++) xa[il] = 0.f;
    #pragma unroll
    for (int t = 0; t < 15; t++){
      int jl = jbase | (t + (t >= i_b ? 1 : 0));
      float c = coeff[t];
      #pragma unroll
      for (int il = 0; il < 16; il++) xa[il] += c*s_v[(grp*16+il)*64 + jl];
    }
    __syncthreads();
    #pragma unroll
    for (int il = 0; il < 16; il++) s_x[nl*68 + grp*16 + il] = xa[il];
  }

  for (int k = tid; k < 4096; k += 256)
    s_h0[(k>>6)*68 + (k&63)] = hid[base*64 + k];
  __syncthreads();

  const float* wih = ws+OFF_WIHC; const float* whc = ws+OFF_WHHC;
  const float* bih = ws+OFF_BIHC; const float* bhc = ws+OFF_BHHC;
  for (int ilb = 0; ilb < 4; ilb++){
    float ac[24];
    #pragma unroll
    for (int p = 0; p < 4; p++){
      int l = grp*16 + ilb*4 + p;
      ac[p*6+0] = bih[l]; ac[p*6+1] = bih[64+l]; ac[p*6+2] = bih[128+l];
      ac[p*6+3] = bhc[l]; ac[p*6+4] = bhc[64+l]; ac[p*6+5] = bhc[128+l];
    }
    #pragma unroll
    for (int dq = 0; dq < 16; dq++){
      float4 x4 = *(const float4*)&s_x [nl*68 + 4*dq];
      float4 h4 = *(const float4*)&s_h0[nl*68 + 4*dq];
      #pragma unroll
      for (int p = 0; p < 4; p++){
        int l = grp*16 + ilb*4 + p;
        const float* w0 = wih + (l     )*64 + 4*dq;
        const float* w1 = wih + (64 + l)*64 + 4*dq;
        const float* w2 = wih + (128+ l)*64 + 4*dq;
        const float* m0 = whc + (l     )*64 + 4*dq;
        const float* m1 = whc + (64 + l)*64 + 4*dq;
        const float* m2 = whc + (128+ l)*64 + 4*dq;
        ac[p*6+0] += x4.x*w0[0]+x4.y*w0[1]+x4.z*w0[2]+x4.w*w0[3];
        ac[p*6+1] += x4.x*w1[0]+x4.y*w1[1]+x4.z*w1[2]+x4.w*w1[3];
        ac[p*6+2] += x4.x*w2[0]+x4.y*w2[1]+x4.z*w2[2]+x4.w*w2[3];
        ac[p*6+3] += h4.x*m0[0]+h4.y*m0[1]+h4.z*m0[2]+h4.w*m0[3];
        ac[p*6+4] += h4.x*m1[0]+h4.y*m1[1]+h4.z*m1[2]+h4.w*m1[3];
        ac[p*6+5] += h4.x*m2[0]+h4.y*m2[1]+h4.z*m2[2]+h4.w*m2[3];
      }
    }
    #pragma unroll
    for (int p = 0; p < 4; p++){
      int l = grp*16 + ilb*4 + p;
      float r = sigf(ac[p*6+0] + ac[p*6+3]);
      float z = sigf(ac[p*6+1] + ac[p*6+4]);
      float n = tanhfast(ac[p*6+2] + r*ac[p*6+5]);
      out[node*64 + l] = (1.0f - z)*n + z*s_h0[nl*68 + l];
    }
  }
}

extern "C" void kernel_launch(void* const* d_in, const int* in_sizes, int n_in,
                              void* d_out, int out_size, void* d_ws, size_t ws_size,
                              hipStream_t stream){
  if (ws_size < (size_t)WS_FLOATS * sizeof(float)) return;
  float* ws = (float*)d_ws;
  // f32 copies still needed (Wih/Whh slots now hold bf16 splits from k_prep2)
  static const int offs[20] = {OFF_WENC, OFF_BENC, 0, 0, OFF_BIHF, OFF_BHHF,
      0, 0, OFF_BIHB, OFF_BHHB, OFF_WHARD, OFF_BHARD, OFF_WQ, OFF_WK, OFF_WV,
      OFF_BV, OFF_WIHC, OFF_WHHC, OFF_BIHC, OFF_BHHC};
  Prep p;
  for (int i = 0; i < 20; i++){
    p.s[i] = (const float*)d_in[3 + i];
    p.n[i] = in_sizes[3 + i];
    p.o[i] = offs[i];
  }
  p.n[2] = 0; p.n[3] = 0; p.n[6] = 0; p.n[7] = 0;   // Wih_f/Whh_f/Wih_b/Whh_b: bf16 path
  hipLaunchKernelGGL(k_prep, dim3(96, 20), dim3(256), 0, stream, p, ws);
  hipLaunchKernelGGL(k_prep2, dim3(96, 5), dim3(256), 0, stream,
                     (const float*)d_in[3], (const float*)d_in[5], (const float*)d_in[9],
                     (const float*)d_in[6], (const float*)d_in[10], ws);
  hipLaunchKernelGGL(k_gru,  dim3(512),    dim3(512), 0, stream,
                     (const float*)d_in[0], ws);
  hipLaunchKernelGGL(k_attn, dim3(256),    dim3(256), 0, stream,
                     (const float*)d_in[0], (const float*)d_in[1],
                     (const float*)d_in[2], ws, (float*)d_out);
}

// Round 2
// 303.360 us; speedup vs baseline: 1.2871x; 1.2505x over previous
//
#include <hip/hip_runtime.h>
#include <hip/hip_bf16.h>
#include <stdint.h>

// B=1024, N=16, D=64, H=64, A=64 -> 16384 nodes. All tensors fp32.
#define NNODE 16384
#define TAU_ 0.01f
#define EPSG 1e-10f

// ---- workspace layout (float offsets); total 1,114,112 floats = 4.25 MB ----
#define OFF_WENC 0
#define OFF_BENC 4096
// bf16 hi/lo weight copies (reuse the old f32 Wih/Whh slots)
#define OFF_WIHF_H 4160      // 192x128 bf16 = 24576 ushort = 12288 fl
#define OFF_WIHF_L 16448
#define OFF_WHHF_H 28736     // 192x64 bf16 = 12288 ushort = 6144 fl
#define OFF_BIHF 41024
#define OFF_BHHF 41216
#define OFF_WIHB_H 41408
#define OFF_WIHB_L 53696
#define OFF_WHHB_H 65984
#define OFF_BIHB 78272
#define OFF_BHHB 78464
#define OFF_WHARD 78656
#define OFF_BHARD 78912
#define OFF_WQ 78914
#define OFF_WK 83010
#define OFF_WV 87106
#define OFF_BV 91202
#define OFF_WIHC 91266
#define OFF_WHHC 103554
#define OFF_BIHC 115842
#define OFF_BHHC 116034
#define OFF_WENCT_H 118784   // Wenc^T bf16 hi: 64x64 = 4096 ushort = 2048 fl
#define OFF_WENCT_L 120832
#define OFF_YF 131072
#define OFF_YB (OFF_YF + 491520)
#define WS_FLOATS (OFF_YB + 491520)

typedef float  v4f __attribute__((ext_vector_type(4)));
typedef short  v8s __attribute__((ext_vector_type(8)));

__device__ __forceinline__ float sigf(float x){ return 1.0f/(1.0f + __expf(-x)); }
__device__ __forceinline__ float tanhfast(float x){ return 1.0f - 2.0f/(__expf(2.0f*x)+1.0f); }
__device__ __forceinline__ unsigned short f2bf(float f){
  __hip_bfloat16 h = __float2bfloat16(f);
  return *reinterpret_cast<unsigned short*>(&h);
}
__device__ __forceinline__ float bf2f(unsigned short u){
  union { unsigned int i; float f; } v; v.i = ((unsigned int)u) << 16; return v.f;
}

// ---------------- K0: copy f32 weights still needed as f32 ----------------
struct Prep {
  const float* s[20];
  int n[20];
  int o[20];
};
__global__ void k_prep(Prep p, float* __restrict__ ws){
  int a = blockIdx.y;
  int i = blockIdx.x * blockDim.x + threadIdx.x;
  if (i < p.n[a]) ws[p.o[a] + i] = p.s[a][i];
}

// ---------------- K0b: bf16 hi/lo splits of the MFMA weights ----------------
// a=0: Wenc^T (transpose+split), a=1/2: Wih_f/Wih_b (flat split),
// a=3/4: Whh_f/Whh_b (hi only; bit-identical to the old f2bf path).
__global__ void k_prep2(const float* __restrict__ wenc,
                        const float* __restrict__ wihf, const float* __restrict__ wihb,
                        const float* __restrict__ whhf, const float* __restrict__ whhb,
                        float* __restrict__ ws){
  int a = blockIdx.y;
  int i = blockIdx.x * blockDim.x + threadIdx.x;
  if (a == 0){
    if (i < 4096){
      float x = wenc[((i & 63) << 6) | (i >> 6)];   // WencT[l][d] = Wenc[d][l]
      unsigned short h = f2bf(x);
      unsigned short l = f2bf(x - bf2f(h));
      ((unsigned short*)(ws + OFF_WENCT_H))[i] = h;
      ((unsigned short*)(ws + OFF_WENCT_L))[i] = l;
    }
  } else if (a == 1 || a == 2){
    if (i < 24576){
      float x = (a == 1 ? wihf : wihb)[i];
      unsigned short h = f2bf(x);
      unsigned short l = f2bf(x - bf2f(h));
      ((unsigned short*)(ws + (a == 1 ? OFF_WIHF_H : OFF_WIHB_H)))[i] = h;
      ((unsigned short*)(ws + (a == 1 ? OFF_WIHF_L : OFF_WIHB_L)))[i] = l;
    }
  } else {
    if (i < 12288){
      float x = (a == 3 ? whhf : whhb)[i];
      ((unsigned short*)(ws + (a == 3 ? OFF_WHHF_H : OFF_WHHB_H)))[i] = f2bf(x);
    }
  }
}

// ---------------- K1: bidirectional 15-step GRU via bf16 MFMA ---------------
// grid 512 (dir = bid>>8).  512 thr = 8 waves; wave w: lw=w>>2, nw=w&3.
// Setup phases (h_enc, u2, cb) are MFMA GEMMs with split-bf16 (hi*hi +
// hi*lo + lo*hi, err ~2^-17 ~= fp32).  Weights pre-split bf16 hi/lo by
// k_prep2 -> frag load = one 16B load.
// launch_bounds arg2 is BLOCKS/CU (CUDA semantics; R1 evidence: arg2=4
// forced VGPR=64 -> 388MB scratch spill traffic).  2 blocks/CU -> VGPR<=128,
// matches the LDS limit (160KB / 71KB = 2 blocks) with zero spill.
__global__ __launch_bounds__(512, 2) void k_gru(const float* __restrict__ obs,
                                                float* __restrict__ ws){
  __shared__ float smem[18176];               // 71 KB -> 2 blocks/CU
  float* s_u2 = smem;                         // [j-node][196] rows g*64+l : 12544
  unsigned short* s_obs_h = (unsigned short*)(smem + 12544); // obs/h_enc hi [64][72]
  unsigned short* s_obs_l = s_obs_h + 4608;                  // lo [64][72]
  unsigned short* s_hbu   = (unsigned short*)(smem + 12544); // loop h: 2 x [64][88] (aliases)

  const int tid = threadIdx.x;
  const int nl  = tid & 63;
  const int grp = __builtin_amdgcn_readfirstlane(tid >> 6);
  const int dir = blockIdx.x >> 8;
  const int base = (blockIdx.x & 255) * 64;
  const int lw = grp >> 2;                    // 0,1 : l-range 32*lw..+32 (loop rows)
  const int nw = grp & 3;                     // node-tile
  const int q  = nl >> 4;                     // quad
  const int i_c = nl & 15;
  const int node = 16*nw + i_c;               // this thread's target node (local)

  // P0: stage obs as bf16 hi/lo, B-frag friendly layout [node][72]
  {
    float4 a = *(const float4*)&obs[base*64 + tid*8];
    float4 b = *(const float4*)&obs[base*64 + tid*8 + 4];
    int nn = tid >> 3, d0 = (tid & 7)*8;
    union { v8s v; unsigned short u[8]; } H, L;
    float xs[8] = {a.x,a.y,a.z,a.w,b.x,b.y,b.z,b.w};
    #pragma unroll
    for (int e = 0; e < 8; e++){
      H.u[e] = f2bf(xs[e]);
      L.u[e] = f2bf(xs[e] - bf2f(H.u[e]));
    }
    *(v8s*)&s_obs_h[nn*72 + d0] = H.v;
    *(v8s*)&s_obs_l[nn*72 + d0] = L.v;
  }
  __syncthreads();

  // P1: h_enc = relu(obs @ Wenc + b_enc) via MFMA.  rows=l (A=Wenc^T), cols=node.
  // Wave (lw,nw): tiles lT = 2*lw+{0,1}, n-tile nw.  In-place write-back.
  const float* benc = ws + OFF_BENC;
  const unsigned short* wtH = (const unsigned short*)(ws + OFF_WENCT_H);
  const unsigned short* wtL = (const unsigned short*)(ws + OFF_WENCT_L);
  v4f dEnc[2];
  {
    v8s obH[2], obL[2];
    #pragma unroll
    for (int kc = 0; kc < 2; kc++){
      int ba = node*72 + kc*32 + q*8;
      obH[kc] = *(const v8s*)&s_obs_h[ba];
      obL[kc] = *(const v8s*)&s_obs_l[ba];
    }
    #pragma unroll
    for (int tt = 0; tt < 2; tt++){
      int lT = 2*lw + tt;
      float4 bi = *(const float4*)&benc[16*lT + 4*q];
      v4f d = (v4f){bi.x, bi.y, bi.z, bi.w};
      #pragma unroll
      for (int kc = 0; kc < 2; kc++){
        int aa = (16*lT + i_c)*64 + kc*32 + q*8;
        v8s aH = *(const v8s*)&wtH[aa];
        v8s aL = *(const v8s*)&wtL[aa];
        d = __builtin_amdgcn_mfma_f32_16x16x32_bf16(aH, obH[kc], d, 0,0,0);
        d = __builtin_amdgcn_mfma_f32_16x16x32_bf16(aH, obL[kc], d, 0,0,0);
        d = __builtin_amdgcn_mfma_f32_16x16x32_bf16(aL, obH[kc], d, 0,0,0);
      }
      dEnc[tt] = d;
    }
  }
  __syncthreads();   // all obs reads done -> safe to overwrite in place
  #pragma unroll
  for (int tt = 0; tt < 2; tt++){
    int lT = 2*lw + tt;
    unsigned short hh[4], ll[4];
    #pragma unroll
    for (int r = 0; r < 4; r++){
      float v = fmaxf(dEnc[tt][r], 0.0f);
      hh[r] = f2bf(v);
      ll[r] = f2bf(v - bf2f(hh[r]));
    }
    int wa = node*72 + 16*lT + 4*q;   // D: col=node, rows 16lT+4q+r (consecutive)
    *(uint2*)&s_obs_h[wa] = make_uint2((unsigned)hh[0] | ((unsigned)hh[1]<<16),
                                       (unsigned)hh[2] | ((unsigned)hh[3]<<16));
    *(uint2*)&s_obs_l[wa] = make_uint2((unsigned)ll[0] | ((unsigned)ll[1]<<16),
                                       (unsigned)ll[2] | ((unsigned)ll[3]<<16));
  }
  __syncthreads();

  const float* bih = ws + (dir ? OFF_BIHB : OFF_BIHF);
  const float* bhh = ws + (dir ? OFF_BHHB : OFF_BHHF);
  const unsigned short* wiH = (const unsigned short*)(ws + (dir ? OFF_WIHB_H : OFF_WIHF_H));
  const unsigned short* wiL = (const unsigned short*)(ws + (dir ? OFF_WIHB_L : OFF_WIHF_L));
  const unsigned short* whH = (const unsigned short*)(ws + (dir ? OFF_WHHB_H : OFF_WHHF_H));

  // shared B-frags: h_enc hi/lo for this wave's node-tile (cols 16nw..)
  v8s hbH[2], hbL[2];
  #pragma unroll
  for (int kc = 0; kc < 2; kc++){
    int ba = node*72 + kc*32 + q*8;
    hbH[kc] = *(const v8s*)&s_obs_h[ba];
    hbL[kc] = *(const v8s*)&s_obs_l[ba];
  }

  // P2a: u2[j][row] = WihR . h_enc[j]  (A = Wih[:,64:128]).  Wave: M-tiles 6lw+m.
  #pragma unroll
  for (int m = 0; m < 6; m++){
    int T = 6*lw + m;
    v4f d = (v4f){0.f,0.f,0.f,0.f};
    #pragma unroll
    for (int kc = 0; kc < 2; kc++){
      int aa = (16*T + i_c)*128 + 64 + kc*32 + q*8;
      v8s aH = *(const v8s*)&wiH[aa];
      v8s aL = *(const v8s*)&wiL[aa];
      d = __builtin_amdgcn_mfma_f32_16x16x32_bf16(aH, hbH[kc], d, 0,0,0);
      d = __builtin_amdgcn_mfma_f32_16x16x32_bf16(aH, hbL[kc], d, 0,0,0);
      d = __builtin_amdgcn_mfma_f32_16x16x32_bf16(aL, hbH[kc], d, 0,0,0);
    }
    *(v4f*)&s_u2[node*196 + 16*T + 4*q] = d;   // rows 16T+4q..+3, col=node
  }

  // P2b: cb = bias + WihL . h_i  -> lands directly in the loop's C-layout.
  // Tile rows 64g+32lw+16t2 (cols 16nw..) = exactly this thread's (l0, node).
  v4f cbr[2], cbz[2], cbn[2], bhn4[2];
  #pragma unroll
  for (int g = 0; g < 3; g++){
    #pragma unroll
    for (int t2 = 0; t2 < 2; t2++){
      int row0 = 64*g + 32*lw + 16*t2 + 4*q;
      float4 bi = *(const float4*)&bih[row0];
      v4f d;
      if (g < 2){
        float4 bh = *(const float4*)&bhh[row0];
        d = (v4f){bi.x+bh.x, bi.y+bh.y, bi.z+bh.z, bi.w+bh.w};
      } else {
        d = (v4f){bi.x, bi.y, bi.z, bi.w};
      }
      int T = (64*g + 32*lw + 16*t2) >> 4;
      #pragma unroll
      for (int kc = 0; kc < 2; kc++){
        int aa = (16*T + i_c)*128 + kc*32 + q*8;   // left half of Wih
        v8s aH = *(const v8s*)&wiH[aa];
        v8s aL = *(const v8s*)&wiL[aa];
        d = __builtin_amdgcn_mfma_f32_16x16x32_bf16(aH, hbH[kc], d, 0,0,0);
        d = __builtin_amdgcn_mfma_f32_16x16x32_bf16(aH, hbL[kc], d, 0,0,0);
        d = __builtin_amdgcn_mfma_f32_16x16x32_bf16(aL, hbH[kc], d, 0,0,0);
      }
      if (g == 0) cbr[t2] = d; else if (g == 1) cbz[t2] = d; else cbn[t2] = d;
    }
  }
  #pragma unroll
  for (int t2 = 0; t2 < 2; t2++){
    int row0 = 128 + 32*lw + 16*t2 + 4*q;
    float4 nh = *(const float4*)&bhh[row0];
    bhn4[t2] = (v4f){nh.x, nh.y, nh.z, nh.w};
  }

  // P2c: Whh -> persistent bf16 A-fragments (pre-split, single 16B load each).
  v8s afr[2][2], afz[2][2], afn[2][2];
  #pragma unroll
  for (int t2 = 0; t2 < 2; t2++){
    #pragma unroll
    for (int kc = 0; kc < 2; kc++){
      #pragma unroll
      for (int g = 0; g < 3; g++){
        int row = g*64 + 32*lw + 16*t2 + i_c;
        v8s a = *(const v8s*)&whH[row*64 + kc*32 + q*8];
        if (g == 0) afr[t2][kc] = a; else if (g == 1) afz[t2][kc] = a; else afn[t2][kc] = a;
      }
    }
  }
  __syncthreads();   // u2 visible; all s_obs reads done; s_hbu (alias) writable

  // P3: 15-step recurrence (h stride 88 ushorts)
  const float* whard = ws + OFF_WHARD + dir*128;
  float* yout        = ws + (dir ? OFF_YB : OFF_YF);

  float hv[8];
  #pragma unroll
  for (int m = 0; m < 8; m++) hv[m] = 0.0f;

  for (int kk = 0; kk < 15; kk++){
    const int t  = dir ? (14 - kk) : kk;
    const int j  = t + (t >= i_c ? 1 : 0);
    const int jl = 16*nw + j;
    const int rb = kk & 1;            // read buffer (valid for kk>0)
    const int wb = (kk + 1) & 1;      // write buffer

    v8s b0, b1;
    if (kk > 0){
      const unsigned short* rp = s_hbu + rb*5632 + node*88 + q*8;
      b0 = *(const v8s*)(rp);
      b1 = *(const v8s*)(rp + 32);
    }

    #pragma unroll
    for (int t2 = 0; t2 < 2; t2++){
      int l0 = 32*lw + 16*t2 + 4*q;
      v4f dr = cbr[t2], dz = cbz[t2];
      v4f dn = (v4f){0.f,0.f,0.f,0.f};
      if (kk > 0){
        dr = __builtin_amdgcn_mfma_f32_16x16x32_bf16(afr[t2][0], b0, dr, 0,0,0);
        dr = __builtin_amdgcn_mfma_f32_16x16x32_bf16(afr[t2][1], b1, dr, 0,0,0);
        dz = __builtin_amdgcn_mfma_f32_16x16x32_bf16(afz[t2][0], b0, dz, 0,0,0);
        dz = __builtin_amdgcn_mfma_f32_16x16x32_bf16(afz[t2][1], b1, dz, 0,0,0);
        dn = __builtin_amdgcn_mfma_f32_16x16x32_bf16(afn[t2][0], b0, dn, 0,0,0);
        dn = __builtin_amdgcn_mfma_f32_16x16x32_bf16(afn[t2][1], b1, dn, 0,0,0);
      }
      v4f ur = *(const v4f*)&s_u2[jl*196 +       l0];
      v4f uz = *(const v4f*)&s_u2[jl*196 +  64 + l0];
      v4f un = *(const v4f*)&s_u2[jl*196 + 128 + l0];
      float hn[4];
      #pragma unroll
      for (int r = 0; r < 4; r++){
        float rg = sigf(dr[r] + ur[r]);
        float zg = sigf(dz[r] + uz[r]);
        float ng = tanhfast(cbn[t2][r] + un[r] + rg*(bhn4[t2][r] + dn[r]));
        float hnew = (1.0f - zg)*ng + zg*hv[t2*4+r];
        hv[t2*4+r] = hnew;
        hn[r] = hnew;
      }
      unsigned int p0 = (unsigned int)f2bf(hn[0]) | ((unsigned int)f2bf(hn[1]) << 16);
      unsigned int p1 = (unsigned int)f2bf(hn[2]) | ((unsigned int)f2bf(hn[3]) << 16);
      *(uint2*)(s_hbu + wb*5632 + node*88 + l0) = make_uint2(p0, p1);
    }
    __syncthreads();

    // reducer: y[node][t] = h_new . W_hard rows (fwd: l, bwd: 64+l)
    if (tid < 64){
      const unsigned short* hb = s_hbu + wb*5632 + tid*88;
      float a0 = 0.f, a1 = 0.f;
      #pragma unroll
      for (int c = 0; c < 16; c++){
        uint2 hw = *(const uint2*)(hb + c*4);
        float f0 = bf2f((unsigned short)(hw.x & 0xffff));
        float f1 = bf2f((unsigned short)(hw.x >> 16));
        float f2 = bf2f((unsigned short)(hw.y & 0xffff));
        float f3 = bf2f((unsigned short)(hw.y >> 16));
        int l = c*4;
        a0 += f0*whard[(l  )*2] + f1*whard[(l+1)*2] + f2*whard[(l+2)*2] + f3*whard[(l+3)*2];
        a1 += f0*whard[(l  )*2+1] + f1*whard[(l+1)*2+1] + f2*whard[(l+2)*2+1] + f3*whard[(l+3)*2+1];
      }
      *(float2*)&yout[((base + tid)*15 + t)*2] = make_float2(a0, a1);
    }
  }
}

// ---------------- K2: qkv + gumbel + attention + final GRU cell -------------
// 256 thr = 4 grps x 16. Sequential low-live passes (unchanged).
__global__ __launch_bounds__(256, 1) void k_attn(const float* __restrict__ obs,
                                                 const float* __restrict__ hid,
                                                 const float* __restrict__ gum,
                                                 float* __restrict__ ws,
                                                 float* __restrict__ out){
  __shared__ float smem[16384];          // 64 KB
  float* s_k  = smem;                    // 4096  [a][node]
  float* s_v  = smem + 4096;             // 4096
  float* s_x  = smem + 8192;             // 4352  [node][68]: obs -> h_enc -> x
  float* s_sp = smem + 12544;            // 3840  score partials
  float* s_h0 = smem;                    // 4352, aliases dead s_k/s_v (late phases)
  const int tid = threadIdx.x;
  const int nl  = tid & 63;
  const int grp = __builtin_amdgcn_readfirstlane(tid >> 6);
  const int base = blockIdx.x * 64;
  const int node = base + nl;

  for (int k = tid; k < 4096; k += 256)
    s_x[(k>>6)*68 + (k&63)] = obs[base*64 + k];
  __syncthreads();

  const float* wenc = ws + OFF_WENC; const float* benc = ws + OFF_BENC;
  {
    float he[16];
    #pragma unroll
    for (int il = 0; il < 16; il++) he[il] = benc[grp*16 + il];
    #pragma unroll
    for (int dq = 0; dq < 16; dq++){
      float4 o4 = *(const float4*)&s_x[nl*68 + 4*dq];
      #pragma unroll
      for (int il = 0; il < 16; il++){
        int l = grp*16 + il;
        he[il] += o4.x*wenc[(4*dq+0)*64+l] + o4.y*wenc[(4*dq+1)*64+l]
                + o4.z*wenc[(4*dq+2)*64+l] + o4.w*wenc[(4*dq+3)*64+l];
      }
    }
    __syncthreads();
    #pragma unroll
    for (int il = 0; il < 16; il++) s_x[nl*68 + grp*16 + il] = fmaxf(he[il], 0.0f);
  }
  __syncthreads();

  const float* wq = ws+OFF_WQ; const float* wk = ws+OFF_WK;
  const float* wv = ws+OFF_WV; const float* bv = ws+OFF_BV;
  {
    float ak[16];
    #pragma unroll
    for (int il = 0; il < 16; il++) ak[il] = 0.f;
    #pragma unroll
    for (int dq = 0; dq < 16; dq++){
      float4 h4 = *(const float4*)&s_x[nl*68 + 4*dq];
      #pragma unroll
      for (int il = 0; il < 16; il++){
        int a = grp*16 + il;
        ak[il] += h4.x*wk[(4*dq+0)*64+a] + h4.y*wk[(4*dq+1)*64+a]
                + h4.z*wk[(4*dq+2)*64+a] + h4.w*wk[(4*dq+3)*64+a];
      }
    }
    #pragma unroll
    for (int il = 0; il < 16; il++) s_k[(grp*16+il)*64 + nl] = ak[il];
  }
  {
    float av[16];
    #pragma unroll
    for (int il = 0; il < 16; il++) av[il] = bv[grp*16+il];
    #pragma unroll
    for (int dq = 0; dq < 16; dq++){
      float4 h4 = *(const float4*)&s_x[nl*68 + 4*dq];
      #pragma unroll
      for (int il = 0; il < 16; il++){
        int a = grp*16 + il;
        av[il] += h4.x*wv[(4*dq+0)*64+a] + h4.y*wv[(4*dq+1)*64+a]
                + h4.z*wv[(4*dq+2)*64+a] + h4.w*wv[(4*dq+3)*64+a];
      }
    }
    #pragma unroll
    for (int il = 0; il < 16; il++) s_v[(grp*16+il)*64 + nl] = fmaxf(av[il], 0.f);
  }
  float aq[16];
  #pragma unroll
  for (int il = 0; il < 16; il++) aq[il] = 0.f;
  #pragma unroll
  for (int dq = 0; dq < 16; dq++){
    float4 h4 = *(const float4*)&s_x[nl*68 + 4*dq];
    #pragma unroll
    for (int il = 0; il < 16; il++){
      int a = grp*16 + il;
      aq[il] += h4.x*wq[(4*dq+0)*64+a] + h4.y*wq[(4*dq+1)*64+a]
              + h4.z*wq[(4*dq+2)*64+a] + h4.w*wq[(4*dq+3)*64+a];
    }
  }
  __syncthreads();

  const int i_b = nl & 15, jbase = nl & 48;
  #pragma unroll
  for (int t = 0; t < 15; t++){
    int jl = jbase | (t + (t >= i_b ? 1 : 0));
    float s = 0.f;
    #pragma unroll
    for (int il = 0; il < 16; il++) s += aq[il]*s_k[(grp*16+il)*64 + jl];
    s_sp[t*256 + grp*64 + nl] = s;
  }
  __syncthreads();

  float coeff[15];
  {
    float sc[15];
    float m = -1e30f;
    #pragma unroll
    for (int t = 0; t < 15; t++){
      float s = (s_sp[t*256+nl] + s_sp[t*256+64+nl] +
                 s_sp[t*256+128+nl] + s_sp[t*256+192+nl]) * 0.125f;
      sc[t] = s; m = fmaxf(m, s);
    }
    float den = 0.f;
    #pragma unroll
    for (int t = 0; t < 15; t++){ sc[t] = __expf(sc[t]-m); den += sc[t]; }
    float rden = 1.0f/den;
    const float bh0 = ws[OFF_BHARD], bh1 = ws[OFF_BHARD+1];
    const float* yF = ws + OFF_YF; const float* yB = ws + OFF_YB;
    #pragma unroll
    for (int t = 0; t < 15; t++){
      int rowb = (node*15 + t)*2;
      float y0 = yF[rowb]   + yB[rowb]   + bh0;
      float y1 = yF[rowb+1] + yB[rowb+1] + bh1;
      float2 u2 = *(const float2*)&gum[rowb];
      float g0 = -__logf(-__logf(u2.x + EPSG) + EPSG);
      float g1 = -__logf(-__logf(u2.y + EPSG) + EPSG);
      float w  = sigf(((y1+g1) - (y0+g0)) * (1.0f/TAU_));
      coeff[t] = sc[t]*rden*w;
    }
  }

  {
    float xa[16];
    #pragma unroll
    for (int il = 0; il < 16; il++) xa[il] = 0.f;
    #pragma unroll
    for (int t = 0; t < 15; t++){
      int jl = jbase | (t + (t >= i_b ? 1 : 0));
      float c = coeff[t];
      #pragma unroll
      for (int il = 0; il < 16; il++) xa[il] += c*s_v[(grp*16+il)*64 + jl];
    }
    __syncthreads();
    #pragma unroll
    for (int il = 0; il < 16; il++) s_x[nl*68 + grp*16 + il] = xa[il];
  }

  for (int k = tid; k < 4096; k += 256)
    s_h0[(k>>6)*68 + (k&63)] = hid[base*64 + k];
  __syncthreads();

  const float* wih = ws+OFF_WIHC; const float* whc = ws+OFF_WHHC;
  const float* bih = ws+OFF_BIHC; const float* bhc = ws+OFF_BHHC;
  for (int ilb = 0; ilb < 4; ilb++){
    float ac[24];
    #pragma unroll
    for (int p = 0; p < 4; p++){
      int l = grp*16 + ilb*4 + p;
      ac[p*6+0] = bih[l]; ac[p*6+1] = bih[64+l]; ac[p*6+2] = bih[128+l];
      ac[p*6+3] = bhc[l]; ac[p*6+4] = bhc[64+l]; ac[p*6+5] = bhc[128+l];
    }
    #pragma unroll
    for (int dq = 0; dq < 16; dq++){
      float4 x4 = *(const float4*)&s_x [nl*68 + 4*dq];
      float4 h4 = *(const float4*)&s_h0[nl*68 + 4*dq];
      #pragma unroll
      for (int p = 0; p < 4; p++){
        int l = grp*16 + ilb*4 + p;
        const float* w0 = wih + (l     )*64 + 4*dq;
        const float* w1 = wih + (64 + l)*64 + 4*dq;
        const float* w2 = wih + (128+ l)*64 + 4*dq;
        const float* m0 = whc + (l     )*64 + 4*dq;
        const float* m1 = whc + (64 + l)*64 + 4*dq;
        const float* m2 = whc + (128+ l)*64 + 4*dq;
        ac[p*6+0] += x4.x*w0[0]+x4.y*w0[1]+x4.z*w0[2]+x4.w*w0[3];
        ac[p*6+1] += x4.x*w1[0]+x4.y*w1[1]+x4.z*w1[2]+x4.w*w1[3];
        ac[p*6+2] += x4.x*w2[0]+x4.y*w2[1]+x4.z*w2[2]+x4.w*w2[3];
        ac[p*6+3] += h4.x*m0[0]+h4.y*m0[1]+h4.z*m0[2]+h4.w*m0[3];
        ac[p*6+4] += h4.x*m1[0]+h4.y*m1[1]+h4.z*m1[2]+h4.w*m1[3];
        ac[p*6+5] += h4.x*m2[0]+h4.y*m2[1]+h4.z*m2[2]+h4.w*m2[3];
      }
    }
    #pragma unroll
    for (int p = 0; p < 4; p++){
      int l = grp*16 + ilb*4 + p;
      float r = sigf(ac[p*6+0] + ac[p*6+3]);
      float z = sigf(ac[p*6+1] + ac[p*6+4]);
      float n = tanhfast(ac[p*6+2] + r*ac[p*6+5]);
      out[node*64 + l] = (1.0f - z)*n + z*s_h0[nl*68 + l];
    }
  }
}

extern "C" void kernel_launch(void* const* d_in, const int* in_sizes, int n_in,
                              void* d_out, int out_size, void* d_ws, size_t ws_size,
                              hipStream_t stream){
  if (ws_size < (size_t)WS_FLOATS * sizeof(float)) return;
  float* ws = (float*)d_ws;
  // f32 copies still needed (Wih/Whh slots now hold bf16 splits from k_prep2)
  static const int offs[20] = {OFF_WENC, OFF_BENC, 0, 0, OFF_BIHF, OFF_BHHF,
      0, 0, OFF_BIHB, OFF_BHHB, OFF_WHARD, OFF_BHARD, OFF_WQ, OFF_WK, OFF_WV,
      OFF_BV, OFF_WIHC, OFF_WHHC, OFF_BIHC, OFF_BHHC};
  Prep p;
  for (int i = 0; i < 20; i++){
    p.s[i] = (const float*)d_in[3 + i];
    p.n[i] = in_sizes[3 + i];
    p.o[i] = offs[i];
  }
  p.n[2] = 0; p.n[3] = 0; p.n[6] = 0; p.n[7] = 0;   // Wih_f/Whh_f/Wih_b/Whh_b: bf16 path
  hipLaunchKernelGGL(k_prep, dim3(96, 20), dim3(256), 0, stream, p, ws);
  hipLaunchKernelGGL(k_prep2, dim3(96, 5), dim3(256), 0, stream,
                     (const float*)d_in[3], (const float*)d_in[5], (const float*)d_in[9],
                     (const float*)d_in[6], (const float*)d_in[10], ws);
  hipLaunchKernelGGL(k_gru,  dim3(512),    dim3(512), 0, stream,
                     (const float*)d_in[0], ws);
  hipLaunchKernelGGL(k_attn, dim3(256),    dim3(256), 0, stream,
                     (const float*)d_in[0], (const float*)d_in[1],
                     (const float*)d_in[2], ws, (float*)d_out);
}